// Round 7
// baseline (173.739 us; speedup 1.0000x reference)
//
#include <hip/hip_runtime.h>
#include <hip/hip_cooperative_groups.h>

namespace cg = cooperative_groups;

#define B_N 8
#define C_N 8
#define F_N 257
#define T_N 2000
#define TQ_N (T_N / 4)      // 500 float4 per (b,f) row
#define EPSF 1e-6f

#define FCH 32              // F chunks for partial sums
#define FPC 9               // ceil(257/32)
#define GBLK 512            // cooperative grid: 2 blocks/CU on 256 CUs
#define BPB  64             // blocks per batch (GBLK / B_N)
#define NTHR 512
#define PER_B (C_N * F_N * TQ_N)   // 1,028,000 float4 per batch
#define STRIDE (BPB * NTHR)        // 32,768

typedef float f32x4 __attribute__((ext_vector_type(4)));

// ============== fused cooperative kernel ==============
__global__ __launch_bounds__(NTHR, 4) void fused_kernel(
    const float* __restrict__ X, const int* __restrict__ ref_ch,
    f32x4* __restrict__ part4 /* [B][FCH][TQ_N] */,
    f32x4* __restrict__ mean4 /* [B][TQ_N] */,
    f32x4* __restrict__ out4)
{
    cg::grid_group grid = cg::this_grid();
    __shared__ f32x4 s_inv4[TQ_N];   // 8 KB
    __shared__ float s_wA[8];
    __shared__ float s_wB[8];

    const int bid = blockIdx.x;
    const int tid = threadIdx.x;
    const int b   = bid >> 6;        // batch
    const int c6  = bid & 63;        // block index within batch

    // ---- Phase A: partial |X[b,rc,f,t]| sums over an F-chunk ----
    if (c6 < FCH && tid < TQ_N) {
        const int rc = ref_ch[0];
        const f32x4* Xb4 =
            (const f32x4*)(X + ((size_t)(b * C_N + rc)) * (size_t)F_N * T_N);
        const int f0 = c6 * FPC;
        const int f1 = (f0 + FPC < F_N) ? (f0 + FPC) : F_N;
        f32x4 acc = {0.f, 0.f, 0.f, 0.f};
        for (int f = f0; f < f1; ++f) {
            f32x4 v = Xb4[f * TQ_N + tid];
            acc.x += fabsf(v.x); acc.y += fabsf(v.y);
            acc.z += fabsf(v.z); acc.w += fabsf(v.w);
        }
        part4[(b * FCH + c6) * TQ_N + tid] = acc;
    }
    grid.sync();

    // ---- Phase B1: reduce 32 chunks -> mean[b][q]. Block c6 owns quads
    //      [c6*8, c6*8+8). Thread (ql, c) loads one partial, shfl-reduce. ----
    if (tid < 256) {
        const int ql = tid >> 5;           // 0..7
        const int c  = tid & 31;           // chunk
        const int q  = c6 * 8 + ql;
        if (q < TQ_N) {
            f32x4 v = part4[(b * FCH + c) * TQ_N + q];
            #pragma unroll
            for (int d = 16; d >= 1; d >>= 1) {
                v.x += __shfl_xor(v.x, d);
                v.y += __shfl_xor(v.y, d);
                v.z += __shfl_xor(v.z, d);
                v.w += __shfl_xor(v.w, d);
            }
            if (c == 0) mean4[b * TQ_N + q] = v * (1.f / (float)F_N);
        }
    }
    grid.sync();

    // ---- Phase B2: redundant per-block affine scan of this block's batch.
    //      mu_t = a_t*mu_{t-1} + (1-a_t)*x_t ; inv stays in LDS. ----
    const float ALPHA = (float)(191.0 / 193.0);
    f32x4 m = {0.f, 0.f, 0.f, 0.f};
    if (tid < TQ_N) m = mean4[b * TQ_N + tid];

    float A = 1.f, Bv = 0.f;
    const int tbase = tid * 4;
    if (tid < TQ_N) {
        #pragma unroll
        for (int k = 0; k < 4; ++k) {
            const float tf = (float)(tbase + k);
            const float a  = fminf((tf - 1.f) / (tf + 1.f), ALPHA);
            Bv = a * Bv + (1.f - a) * m[k];
            A  = a * A;
        }
    }
    const int lane = tid & 63;
    #pragma unroll
    for (int d = 1; d < 64; d <<= 1) {
        const float pA = __shfl_up(A, d);
        const float pB = __shfl_up(Bv, d);
        if (lane >= d) { Bv = A * pB + Bv; A = A * pA; }
    }
    const int wid = tid >> 6;
    if (lane == 63) { s_wA[wid] = A; s_wB[wid] = Bv; }
    __syncthreads();
    if (tid == 0) {
        float cA = 1.f, cB = 0.f;
        #pragma unroll
        for (int w = 0; w < 8; ++w) {
            const float nA = s_wA[w] * cA;
            const float nB = s_wA[w] * cB + s_wB[w];
            s_wA[w] = cA; s_wB[w] = cB;
            cA = nA; cB = nB;
        }
    }
    __syncthreads();
    float eA = __shfl_up(A, 1);
    float eB = __shfl_up(Bv, 1);
    if (lane == 0) { eA = 1.f; eB = 0.f; }
    float mu = eA * s_wB[wid] + eB;     // applied to mu0 = 0

    if (tid < TQ_N) {
        f32x4 r;
        #pragma unroll
        for (int k = 0; k < 4; ++k) {
            const float tf = (float)(tbase + k);
            const float a  = fminf((tf - 1.f) / (tf + 1.f), ALPHA);
            mu = a * mu + (1.f - a) * m[k];
            r[k] = 1.f / (mu + EPSF);
        }
        s_inv4[tid] = r;
    }
    __syncthreads();

    // ---- Phase C: streaming out = X * inv[b,t], inv from LDS ----
    const f32x4* Xb = (const f32x4*)X + (size_t)b * PER_B;
    f32x4*       Ob = out4 + (size_t)b * PER_B;

    int i  = c6 * NTHR + tid;
    int tq = i % TQ_N;
    const int DT = STRIDE % TQ_N;       // 268
    #pragma unroll 4
    for (int it = 0; it < 31; ++it) {   // 31 full strides for every thread
        Ob[i] = Xb[i] * s_inv4[tq];
        i += STRIDE;
        tq += DT; if (tq >= TQ_N) tq -= TQ_N;
    }
    if (i < PER_B) Ob[i] = Xb[i] * s_inv4[tq];
}

// ============== fallback path (3 kernels, proven 55.5 us) ==============
__global__ __launch_bounds__(512) void partial_mean_kernel(
    const float* __restrict__ X, const int* __restrict__ ref_ch,
    f32x4* __restrict__ part4)
{
    const int b = blockIdx.x, c = blockIdx.y, tid = threadIdx.x;
    if (tid >= TQ_N) return;
    const int rc = ref_ch[0];
    const f32x4* Xb4 =
        (const f32x4*)(X + ((size_t)(b * C_N + rc)) * (size_t)F_N * T_N);
    const int f0 = c * FPC;
    const int f1 = (f0 + FPC < F_N) ? (f0 + FPC) : F_N;
    f32x4 acc = {0.f, 0.f, 0.f, 0.f};
    for (int f = f0; f < f1; ++f) {
        f32x4 v = Xb4[f * TQ_N + tid];
        acc.x += fabsf(v.x); acc.y += fabsf(v.y);
        acc.z += fabsf(v.z); acc.w += fabsf(v.w);
    }
    part4[(b * FCH + c) * TQ_N + tid] = acc;
}

__global__ __launch_bounds__(512) void scan_kernel(
    const f32x4* __restrict__ part4, f32x4* __restrict__ inv4)
{
    __shared__ float s_mean[T_N];
    __shared__ float s_wA[8];
    __shared__ float s_wB[8];
    const float ALPHA = (float)(191.0 / 193.0);
    const int b = blockIdx.x, tid = threadIdx.x;

    if (tid < TQ_N) {
        f32x4 s = {0.f, 0.f, 0.f, 0.f};
        #pragma unroll
        for (int c = 0; c < FCH; ++c) s += part4[(b * FCH + c) * TQ_N + tid];
        const int t = tid * 4;
        const float inv_f = 1.f / (float)F_N;
        s_mean[t + 0] = s.x * inv_f; s_mean[t + 1] = s.y * inv_f;
        s_mean[t + 2] = s.z * inv_f; s_mean[t + 3] = s.w * inv_f;
    }
    __syncthreads();

    float A = 1.f, Bv = 0.f;
    const int tbase = tid * 4;
    #pragma unroll
    for (int k = 0; k < 4; ++k) {
        const int t = tbase + k;
        if (t < T_N) {
            const float tf = (float)t;
            const float a = fminf((tf - 1.f) / (tf + 1.f), ALPHA);
            Bv = a * Bv + (1.f - a) * s_mean[t];
            A  = a * A;
        }
    }
    const int lane = tid & 63;
    #pragma unroll
    for (int d = 1; d < 64; d <<= 1) {
        const float pA = __shfl_up(A, d);
        const float pB = __shfl_up(Bv, d);
        if (lane >= d) { Bv = A * pB + Bv; A = A * pA; }
    }
    const int wid = tid >> 6;
    if (lane == 63) { s_wA[wid] = A; s_wB[wid] = Bv; }
    __syncthreads();
    if (tid == 0) {
        float cA = 1.f, cB = 0.f;
        #pragma unroll
        for (int w = 0; w < 8; ++w) {
            const float nA = s_wA[w] * cA;
            const float nB = s_wA[w] * cB + s_wB[w];
            s_wA[w] = cA; s_wB[w] = cB;
            cA = nA; cB = nB;
        }
    }
    __syncthreads();
    float eA = __shfl_up(A, 1);
    float eB = __shfl_up(Bv, 1);
    if (lane == 0) { eA = 1.f; eB = 0.f; }
    float mu = eA * s_wB[wid] + eB;

    if (tid < TQ_N) {
        f32x4 r;
        #pragma unroll
        for (int k = 0; k < 4; ++k) {
            const int t = tbase + k;
            const float tf = (float)t;
            const float a = fminf((tf - 1.f) / (tf + 1.f), ALPHA);
            mu = a * mu + (1.f - a) * s_mean[t];
            r[k] = 1.f / (mu + EPSF);
        }
        inv4[b * TQ_N + tid] = r;
    }
}

__global__ __launch_bounds__(256) void norm_kernel(
    const f32x4* __restrict__ X4, const f32x4* __restrict__ inv4,
    f32x4* __restrict__ out4)
{
    const int i = blockIdx.x * 256 + threadIdx.x;
    if (i >= PER_B) return;
    const int b  = blockIdx.y;
    const int tq = i % TQ_N;
    const size_t g = (size_t)b * PER_B + i;
    out4[g] = X4[g] * inv4[b * TQ_N + tq];
}

// ============== launch ==============
extern "C" void kernel_launch(void* const* d_in, const int* in_sizes, int n_in,
                              void* d_out, int out_size, void* d_ws, size_t ws_size,
                              hipStream_t stream) {
    const float* X  = (const float*)d_in[0];
    const int*   rc = (const int*)d_in[1];

    f32x4* part = (f32x4*)d_ws;                        // 8*32*500*16 = 2.048 MB
    f32x4* mean = part + B_N * FCH * TQ_N;             // 8*500*16   = 64 KB
    f32x4* out  = (f32x4*)d_out;

    // Gate the cooperative path on guaranteed co-residency (deterministic).
    int nb = 0;
    hipError_t qe = hipOccupancyMaxActiveBlocksPerMultiprocessor(
        &nb, fused_kernel, NTHR, 0);
    bool coop_ok = (qe == hipSuccess) && (nb * 256 >= GBLK);

    if (coop_ok) {
        void* args[5] = {(void*)&X, (void*)&rc, (void*)&part,
                         (void*)&mean, (void*)&out};
        hipError_t le = hipLaunchCooperativeKernel(
            fused_kernel, dim3(GBLK), dim3(NTHR), args, 0, stream);
        if (le == hipSuccess) return;
    }

    // Fallback: proven 3-kernel pipeline.
    dim3 gA(B_N, FCH);
    partial_mean_kernel<<<gA, 512, 0, stream>>>(X, rc, part);
    scan_kernel<<<B_N, 512, 0, stream>>>(part, mean);
    dim3 gC((PER_B + 255) / 256, B_N);
    norm_kernel<<<gC, 256, 0, stream>>>((const f32x4*)X, mean, out);
}

// Round 8
// 65.402 us; speedup vs baseline: 2.6565x; 2.6565x over previous
//
#include <hip/hip_runtime.h>

#define B_N 8
#define C_N 8
#define F_N 257
#define T_N 2000
#define TQ_N (T_N / 4)      // 500 float4 per (b,f) row
#define EPSF 1e-6f

#define FCH 32              // F chunks
#define FPC 9               // ceil(257/32) rows per chunk
#define PER_B (C_N * F_N * TQ_N)   // 1,028,000 float4 per batch

// norm kernel geometry: 256 blocks/batch * 8 batches = 2048 blocks,
// 256 thr => 65536 threads/batch, ~16 float4 per thread grid-stride.
#define NBPB   256
#define NTHR_C 256
#define CSTRIDE (NBPB * NTHR_C)    // 65536
#define CDT     (CSTRIDE % TQ_N)   // 36

typedef float f32x4 __attribute__((ext_vector_type(4)));

// ---- Kernel A: partial |X[b,rc,f,t]| sums over an F-chunk. 256 blocks. ----
__global__ __launch_bounds__(512) void partial_mean_kernel(
    const float* __restrict__ X, const int* __restrict__ ref_ch,
    f32x4* __restrict__ part4 /* [B][FCH][TQ_N] */)
{
    const int b = blockIdx.x, c = blockIdx.y, tid = threadIdx.x;
    if (tid >= TQ_N) return;

    const int rc = ref_ch[0];
    const f32x4* Xb4 =
        (const f32x4*)(X + ((size_t)(b * C_N + rc)) * (size_t)F_N * T_N);

    const int f0 = c * FPC;
    const int f1 = (f0 + FPC < F_N) ? (f0 + FPC) : F_N;

    f32x4 acc = {0.f, 0.f, 0.f, 0.f};
    for (int f = f0; f < f1; ++f) {
        f32x4 v = Xb4[f * TQ_N + tid];
        acc.x += fabsf(v.x); acc.y += fabsf(v.y);
        acc.z += fabsf(v.z); acc.w += fabsf(v.w);
    }
    part4[(b * FCH + c) * TQ_N + tid] = acc;
}

// ---- Kernel B: reduce partials -> mean, parallel affine scan ->
//      inv[b][t] = 1/(mu_t + eps). One block per batch. ----
__global__ __launch_bounds__(512) void scan_kernel(
    const f32x4* __restrict__ part4,
    f32x4* __restrict__ inv4 /* [B][TQ_N] */)
{
    __shared__ float s_mean[T_N];
    __shared__ float s_wA[8];
    __shared__ float s_wB[8];
    const float ALPHA = (float)(191.0 / 193.0);
    const int b = blockIdx.x, tid = threadIdx.x;

    if (tid < TQ_N) {
        f32x4 s = {0.f, 0.f, 0.f, 0.f};
        #pragma unroll
        for (int c = 0; c < FCH; ++c)
            s += part4[(b * FCH + c) * TQ_N + tid];
        const int t = tid * 4;
        const float inv_f = 1.f / (float)F_N;
        s_mean[t + 0] = s.x * inv_f; s_mean[t + 1] = s.y * inv_f;
        s_mean[t + 2] = s.z * inv_f; s_mean[t + 3] = s.w * inv_f;
    }
    __syncthreads();

    // Affine scan: transform (A,B): mu -> A*mu + B. Local composite of 4 t's.
    float A = 1.f, Bv = 0.f;
    const int tbase = tid * 4;
    #pragma unroll
    for (int k = 0; k < 4; ++k) {
        const int t = tbase + k;
        if (t < T_N) {
            const float tf = (float)t;
            const float a = fminf((tf - 1.f) / (tf + 1.f), ALPHA);
            Bv = a * Bv + (1.f - a) * s_mean[t];
            A  = a * A;
        }
    }
    const int lane = tid & 63;
    #pragma unroll
    for (int d = 1; d < 64; d <<= 1) {
        const float pA = __shfl_up(A, d);
        const float pB = __shfl_up(Bv, d);
        if (lane >= d) { Bv = A * pB + Bv; A = A * pA; }
    }
    const int wid = tid >> 6;
    if (lane == 63) { s_wA[wid] = A; s_wB[wid] = Bv; }
    __syncthreads();
    if (tid == 0) {
        float cA = 1.f, cB = 0.f;
        #pragma unroll
        for (int w = 0; w < 8; ++w) {
            const float nA = s_wA[w] * cA;
            const float nB = s_wA[w] * cB + s_wB[w];
            s_wA[w] = cA; s_wB[w] = cB;
            cA = nA; cB = nB;
        }
    }
    __syncthreads();
    float eA = __shfl_up(A, 1);
    float eB = __shfl_up(Bv, 1);
    if (lane == 0) { eA = 1.f; eB = 0.f; }
    float mu = eA * s_wB[wid] + eB;   // applied to mu0 = 0

    if (tid < TQ_N) {
        f32x4 r;
        #pragma unroll
        for (int k = 0; k < 4; ++k) {
            const int t = tbase + k;
            const float tf = (float)t;
            const float a = fminf((tf - 1.f) / (tf + 1.f), ALPHA);
            mu = a * mu + (1.f - a) * s_mean[t];
            r[k] = 1.f / (mu + EPSF);
        }
        inv4[b * TQ_N + tid] = r;
    }
}

// ---- Kernel C: streaming out = X * inv[b,t]. Grid-stride, 8 blocks/CU,
//      ~16 float4 per thread; incremental tq avoids per-element mod. ----
__global__ __launch_bounds__(NTHR_C) void norm_kernel(
    const f32x4* __restrict__ X4,
    const f32x4* __restrict__ inv4,
    f32x4* __restrict__ out4)
{
    const int b = blockIdx.y;
    const f32x4* Xb  = X4   + (size_t)b * PER_B;
    f32x4*       Ob  = out4 + (size_t)b * PER_B;
    const f32x4* ivb = inv4 + b * TQ_N;

    int i  = blockIdx.x * NTHR_C + threadIdx.x;
    int tq = i % TQ_N;
    for (; i < PER_B; i += CSTRIDE) {
        Ob[i] = Xb[i] * ivb[tq];
        tq += CDT; if (tq >= TQ_N) tq -= TQ_N;
    }
}

extern "C" void kernel_launch(void* const* d_in, const int* in_sizes, int n_in,
                              void* d_out, int out_size, void* d_ws, size_t ws_size,
                              hipStream_t stream) {
    const float* X  = (const float*)d_in[0];
    const int*   rc = (const int*)d_in[1];

    f32x4* inv  = (f32x4*)d_ws;                 // 8*500*16      = 64 KB
    f32x4* part = inv + B_N * TQ_N;             // 8*32*500*16   = 2.048 MB

    dim3 gA(B_N, FCH);
    partial_mean_kernel<<<gA, 512, 0, stream>>>(X, rc, part);

    scan_kernel<<<B_N, 512, 0, stream>>>(part, inv);

    dim3 gC(NBPB, B_N);
    norm_kernel<<<gC, NTHR_C, 0, stream>>>((const f32x4*)X, inv, (f32x4*)d_out);
}

// Round 9
// 63.221 us; speedup vs baseline: 2.7481x; 1.0345x over previous
//
#include <hip/hip_runtime.h>

#define B_N 8
#define C_N 8
#define F_N 257
#define T_N 2000
#define TQ_N (T_N / 4)      // 500 float4 per (b,f) row
#define EPSF 1e-6f
#define PER_B (C_N * F_N * TQ_N)   // 1,028,000 float4 per batch

typedef float f32x4 __attribute__((ext_vector_type(4)));

// ---- Kernel A': direct mean over F of |X[b,rc,f,t]|.
//      grid (B_N, 32); 512 thr = 32 f-groups x 16 quads; LDS tree reduce. ----
__global__ __launch_bounds__(512) void mean_kernel(
    const float* __restrict__ X, const int* __restrict__ ref_ch,
    f32x4* __restrict__ mean4 /* [B][TQ_N] */)
{
    __shared__ f32x4 s_red[512];   // 8 KB
    const int b   = blockIdx.x;
    const int qb  = blockIdx.y * 16;
    const int tid = threadIdx.x;
    const int fi  = tid >> 4;      // f-group 0..31
    const int qi  = tid & 15;      // quad within block
    const int q   = qb + qi;

    const int rc = ref_ch[0];
    const f32x4* Xb4 =
        (const f32x4*)(X + ((size_t)(b * C_N + rc)) * (size_t)F_N * T_N);

    f32x4 acc = {0.f, 0.f, 0.f, 0.f};
    if (q < TQ_N) {
        for (int f = fi; f < F_N; f += 32) {
            f32x4 v = Xb4[f * TQ_N + q];
            acc.x += fabsf(v.x); acc.y += fabsf(v.y);
            acc.z += fabsf(v.z); acc.w += fabsf(v.w);
        }
    }
    s_red[tid] = acc;
    __syncthreads();
    // tree-reduce across the 32 f-groups (stride-16 layout folds cleanly)
    #pragma unroll
    for (int s = 256; s >= 16; s >>= 1) {
        if (tid < s) s_red[tid] += s_red[tid + s];
        __syncthreads();
    }
    if (tid < 16) {
        const int qq = qb + tid;
        if (qq < TQ_N)
            mean4[b * TQ_N + qq] = s_red[tid] * (1.f / (float)F_N);
    }
}

// ---- Kernel C': per-block redundant affine scan (from mean, 8 KB) -> LDS,
//      then one-shot streaming out = X * inv[tq]. ----
__global__ __launch_bounds__(512) void norm_scan_kernel(
    const f32x4* __restrict__ X4,
    const f32x4* __restrict__ mean4,
    f32x4* __restrict__ out4)
{
    __shared__ f32x4 s_inv4[TQ_N];   // 8 KB
    __shared__ float s_wA[8];
    __shared__ float s_wB[8];
    const float ALPHA = (float)(191.0 / 193.0);

    const int b   = blockIdx.y;
    const int tid = threadIdx.x;

    const f32x4* Xb = X4   + (size_t)b * PER_B;
    f32x4*       Ob = out4 + (size_t)b * PER_B;

    // Issue the streaming load FIRST; scan hides under its latency.
    const int  i     = blockIdx.x * 512 + tid;
    const bool valid = (i < PER_B);
    f32x4 x = {0.f, 0.f, 0.f, 0.f};
    int   tq = 0;
    if (valid) { x = Xb[i]; tq = i % TQ_N; }

    // ---- redundant affine scan of this batch's mean (proven code) ----
    f32x4 m = {0.f, 0.f, 0.f, 0.f};
    if (tid < TQ_N) m = mean4[b * TQ_N + tid];

    float A = 1.f, Bv = 0.f;
    const int tbase = tid * 4;
    if (tid < TQ_N) {
        #pragma unroll
        for (int k = 0; k < 4; ++k) {
            const float tf = (float)(tbase + k);
            const float a  = fminf((tf - 1.f) / (tf + 1.f), ALPHA);
            Bv = a * Bv + (1.f - a) * m[k];
            A  = a * A;
        }
    }
    const int lane = tid & 63;
    #pragma unroll
    for (int d = 1; d < 64; d <<= 1) {
        const float pA = __shfl_up(A, d);
        const float pB = __shfl_up(Bv, d);
        if (lane >= d) { Bv = A * pB + Bv; A = A * pA; }
    }
    const int wid = tid >> 6;
    if (lane == 63) { s_wA[wid] = A; s_wB[wid] = Bv; }
    __syncthreads();
    if (tid == 0) {
        float cA = 1.f, cB = 0.f;
        #pragma unroll
        for (int w = 0; w < 8; ++w) {
            const float nA = s_wA[w] * cA;
            const float nB = s_wA[w] * cB + s_wB[w];
            s_wA[w] = cA; s_wB[w] = cB;
            cA = nA; cB = nB;
        }
    }
    __syncthreads();
    float eA = __shfl_up(A, 1);
    float eB = __shfl_up(Bv, 1);
    if (lane == 0) { eA = 1.f; eB = 0.f; }
    float mu = eA * s_wB[wid] + eB;     // applied to mu0 = 0

    if (tid < TQ_N) {
        f32x4 r;
        #pragma unroll
        for (int k = 0; k < 4; ++k) {
            const float tf = (float)(tbase + k);
            const float a  = fminf((tf - 1.f) / (tf + 1.f), ALPHA);
            mu = a * mu + (1.f - a) * m[k];
            r[k] = 1.f / (mu + EPSF);
        }
        s_inv4[tid] = r;
    }
    __syncthreads();

    // ---- stream ----
    if (valid) Ob[i] = x * s_inv4[tq];
}

extern "C" void kernel_launch(void* const* d_in, const int* in_sizes, int n_in,
                              void* d_out, int out_size, void* d_ws, size_t ws_size,
                              hipStream_t stream) {
    const float* X  = (const float*)d_in[0];
    const int*   rc = (const int*)d_in[1];

    f32x4* mean = (f32x4*)d_ws;   // 8*500*16 = 64 KB

    dim3 gA(B_N, 32);
    mean_kernel<<<gA, 512, 0, stream>>>(X, rc, mean);

    dim3 gC((PER_B + 511) / 512, B_N);   // 2008 x 8 one-shot blocks
    norm_scan_kernel<<<gC, 512, 0, stream>>>(
        (const f32x4*)X, (const f32x4*)mean, (f32x4*)d_out);
}

// Round 10
// 52.843 us; speedup vs baseline: 3.2878x; 1.1964x over previous
//
#include <hip/hip_runtime.h>

#define B_N 8
#define C_N 8
#define F_N 257
#define T_N 2000
#define TQ_N (T_N / 4)      // 500 float4 per (b,f) row
#define EPSF 1e-6f
#define PER_B (C_N * F_N * TQ_N)   // 1,028,000 float4 per batch

#define FCH 32              // F chunks
#define FPC 9               // ceil(257/32) rows per chunk

typedef float f32x4 __attribute__((ext_vector_type(4)));

// ---- Kernel A: partial |X[b,rc,f,t]| sums over an F-chunk. 256 blocks. ----
__global__ __launch_bounds__(512) void partial_mean_kernel(
    const float* __restrict__ X, const int* __restrict__ ref_ch,
    f32x4* __restrict__ part4 /* [B][FCH][TQ_N] */)
{
    const int b = blockIdx.x, c = blockIdx.y, tid = threadIdx.x;
    if (tid >= TQ_N) return;

    const int rc = ref_ch[0];
    const f32x4* Xb4 =
        (const f32x4*)(X + ((size_t)(b * C_N + rc)) * (size_t)F_N * T_N);

    const int f0 = c * FPC;
    const int f1 = (f0 + FPC < F_N) ? (f0 + FPC) : F_N;

    f32x4 acc = {0.f, 0.f, 0.f, 0.f};
    for (int f = f0; f < f1; ++f) {
        f32x4 v = Xb4[f * TQ_N + tid];
        acc.x += fabsf(v.x); acc.y += fabsf(v.y);
        acc.z += fabsf(v.z); acc.w += fabsf(v.w);
    }
    part4[(b * FCH + c) * TQ_N + tid] = acc;
}

// ---- Kernel B: reduce partials -> mean, parallel affine scan ->
//      inv[b][t] = 1/(mu_t + eps). One block per batch. ----
__global__ __launch_bounds__(512) void scan_kernel(
    const f32x4* __restrict__ part4,
    f32x4* __restrict__ inv4 /* [B][TQ_N] */)
{
    __shared__ float s_mean[T_N];
    __shared__ float s_wA[8];
    __shared__ float s_wB[8];
    const float ALPHA = (float)(191.0 / 193.0);
    const int b = blockIdx.x, tid = threadIdx.x;

    if (tid < TQ_N) {
        f32x4 s = {0.f, 0.f, 0.f, 0.f};
        #pragma unroll
        for (int c = 0; c < FCH; ++c)
            s += part4[(b * FCH + c) * TQ_N + tid];
        const int t = tid * 4;
        const float inv_f = 1.f / (float)F_N;
        s_mean[t + 0] = s.x * inv_f; s_mean[t + 1] = s.y * inv_f;
        s_mean[t + 2] = s.z * inv_f; s_mean[t + 3] = s.w * inv_f;
    }
    __syncthreads();

    // Affine scan: transform (A,B): mu -> A*mu + B. Local composite of 4 t's.
    float A = 1.f, Bv = 0.f;
    const int tbase = tid * 4;
    #pragma unroll
    for (int k = 0; k < 4; ++k) {
        const int t = tbase + k;
        if (t < T_N) {
            const float tf = (float)t;
            const float a = fminf((tf - 1.f) / (tf + 1.f), ALPHA);
            Bv = a * Bv + (1.f - a) * s_mean[t];
            A  = a * A;
        }
    }
    const int lane = tid & 63;
    #pragma unroll
    for (int d = 1; d < 64; d <<= 1) {
        const float pA = __shfl_up(A, d);
        const float pB = __shfl_up(Bv, d);
        if (lane >= d) { Bv = A * pB + Bv; A = A * pA; }
    }
    const int wid = tid >> 6;
    if (lane == 63) { s_wA[wid] = A; s_wB[wid] = Bv; }
    __syncthreads();
    if (tid == 0) {
        float cA = 1.f, cB = 0.f;
        #pragma unroll
        for (int w = 0; w < 8; ++w) {
            const float nA = s_wA[w] * cA;
            const float nB = s_wA[w] * cB + s_wB[w];
            s_wA[w] = cA; s_wB[w] = cB;
            cA = nA; cB = nB;
        }
    }
    __syncthreads();
    float eA = __shfl_up(A, 1);
    float eB = __shfl_up(Bv, 1);
    if (lane == 0) { eA = 1.f; eB = 0.f; }
    float mu = eA * s_wB[wid] + eB;   // applied to mu0 = 0

    if (tid < TQ_N) {
        f32x4 r;
        #pragma unroll
        for (int k = 0; k < 4; ++k) {
            const int t = tbase + k;
            const float tf = (float)t;
            const float a = fminf((tf - 1.f) / (tf + 1.f), ALPHA);
            mu = a * mu + (1.f - a) * s_mean[t];
            r[k] = 1.f / (mu + EPSF);
        }
        inv4[b * TQ_N + tid] = r;
    }
}

// ---- Kernel C: one-shot streaming out = X * inv[b,t].
//      Cached load of X (keep it L3-resident across replays);
//      NON-TEMPORAL store of out (don't let out evict X from L3). ----
__global__ __launch_bounds__(256) void norm_kernel(
    const f32x4* __restrict__ X4,
    const f32x4* __restrict__ inv4,
    f32x4* __restrict__ out4)
{
    const int N4 = B_N * PER_B;
    const int idx = blockIdx.x * 256 + threadIdx.x;
    if (idx >= N4) return;

    const int b  = idx / PER_B;
    const int tq = idx % TQ_N;

    const f32x4 iv = inv4[b * TQ_N + tq];
    const f32x4 x  = X4[idx];                       // cached (L3-friendly)
    __builtin_nontemporal_store(x * iv, out4 + idx);  // streaming store
}

extern "C" void kernel_launch(void* const* d_in, const int* in_sizes, int n_in,
                              void* d_out, int out_size, void* d_ws, size_t ws_size,
                              hipStream_t stream) {
    const float* X  = (const float*)d_in[0];
    const int*   rc = (const int*)d_in[1];

    f32x4* inv  = (f32x4*)d_ws;                 // 8*500*16      = 64 KB
    f32x4* part = inv + B_N * TQ_N;             // 8*32*500*16   = 2.048 MB

    dim3 gA(B_N, FCH);
    partial_mean_kernel<<<gA, 512, 0, stream>>>(X, rc, part);

    scan_kernel<<<B_N, 512, 0, stream>>>(part, inv);

    const int N4 = B_N * PER_B;
    norm_kernel<<<(N4 + 255) / 256, 256, 0, stream>>>(
        (const f32x4*)X, inv, (f32x4*)d_out);
}